// Round 9
// baseline (1586.826 us; speedup 1.0000x reference)
//
#include <hip/hip_runtime.h>
#include <hip/hip_bf16.h>

#define B_ 2
#define N_ 1024
#define D_ 768
#define E_ 128
#define H_ 16
#define HD_ 48
#define HDP_ 64

// instrumentation: attn repeated in-kernel (idempotent); bias launched twice.
#define ATTN_REPS 16

typedef short bf16x8 __attribute__((ext_vector_type(8)));
typedef float f32x4 __attribute__((ext_vector_type(4)));

__device__ __forceinline__ unsigned short f2bf(float f) {
    __hip_bfloat16 h = __float2bfloat16(f);
    return *reinterpret_cast<unsigned short*>(&h);
}
__device__ __forceinline__ float bf2f(unsigned short s) {
    return __uint_as_float(((unsigned int)s) << 16);
}

// ---------------------------------------------------------------------------
// Kernel 0: conv_prep — all input conversions in one coalesced pass.
// ---------------------------------------------------------------------------
__global__ __launch_bounds__(256) void conv_prep(
    const float* __restrict__ node, const float* __restrict__ kin,
    const float* __restrict__ Wq, const float* __restrict__ Wk,
    const float* __restrict__ Wv, const float* __restrict__ Wg,
    const float* __restrict__ Wo,
    unsigned short* __restrict__ nb, unsigned short* __restrict__ kb,
    unsigned short* __restrict__ WqB, unsigned short* __restrict__ WkB,
    unsigned short* __restrict__ WvB, unsigned short* __restrict__ WgB,
    unsigned short* __restrict__ Whi, unsigned short* __restrict__ Wlo,
    unsigned short* __restrict__ qp, unsigned short* __restrict__ kp)
{
    const int y = blockIdx.y;
    const int t = blockIdx.x * 256 + threadIdx.x;
    if (y < 6) {
        const int n = (y < 2) ? (B_ * N_ * D_) : (D_ * D_);
        const int i4 = t * 4;
        if (i4 < n) {
            const float* s = (y == 0) ? node : (y == 1) ? kin :
                             (y == 2) ? Wq : (y == 3) ? Wk : (y == 4) ? Wv : Wg;
            unsigned short* d = (y == 0) ? nb : (y == 1) ? kb :
                                (y == 2) ? WqB : (y == 3) ? WkB : (y == 4) ? WvB : WgB;
            const float4 v = *(const float4*)(s + i4);
            ushort4 o;
            o.x = f2bf(v.x); o.y = f2bf(v.y); o.z = f2bf(v.z); o.w = f2bf(v.w);
            *(ushort4*)(d + i4) = o;
        }
    } else if (y == 6) {
        const int i4 = t * 4;
        if (i4 < D_ * D_) {
            const float4 v = *(const float4*)(Wo + i4);
            ushort4 hi, lo;
            hi.x = f2bf(v.x); lo.x = f2bf(v.x - bf2f(hi.x));
            hi.y = f2bf(v.y); lo.y = f2bf(v.y - bf2f(hi.y));
            hi.z = f2bf(v.z); lo.z = f2bf(v.z - bf2f(hi.z));
            hi.w = f2bf(v.w); lo.w = f2bf(v.w - bf2f(hi.w));
            *(ushort4*)(Whi + i4) = hi;
            *(ushort4*)(Wlo + i4) = lo;
        }
    } else {
        if (t < B_ * H_ * N_ * 2) {
            const int row = t >> 1, half = t & 1;
            uint4 z = {0u, 0u, 0u, 0u};
            *(uint4*)(qp + ((size_t)row << 6) + 48 + half * 8) = z;
            *(uint4*)(kp + ((size_t)row << 6) + 48 + half * 8) = z;
        }
    }
}

// ---------------------------------------------------------------------------
// Kernel 1: projections from pre-converted bf16 (2x K-unroll).
// ---------------------------------------------------------------------------
__global__ __launch_bounds__(256) void proj_kernel(
    const unsigned short* __restrict__ nb, const unsigned short* __restrict__ kb,
    const unsigned short* __restrict__ WqB, const unsigned short* __restrict__ WkB,
    const unsigned short* __restrict__ WvB, const unsigned short* __restrict__ WgB,
    const float* __restrict__ bq,
    unsigned short* __restrict__ qp, unsigned short* __restrict__ kp,
    unsigned short* __restrict__ vT, float* __restrict__ g)
{
    const int z = blockIdx.z;
    const int lane = threadIdx.x & 63;
    const int w = threadIdx.x >> 6;
    const int wm = w >> 1, wn = w & 1;
    const int lr = lane & 15, lg = lane >> 4;

    const unsigned short* A;
    const unsigned short* Wm;
    int mbase, nbase;
    if (z == 2) {
        A = WvB; Wm = kb;
        mbase = blockIdx.y * 64 + wm * 32;
        nbase = blockIdx.x * 64 + wn * 32;
    } else {
        A = (z == 1) ? kb : nb;
        Wm = (z == 0) ? WqB : (z == 1) ? WkB : WgB;
        mbase = blockIdx.x * 64 + wm * 32;
        nbase = blockIdx.y * 64 + wn * 32;
    }

    f32x4 acc[2][2] = {};
    for (int k0 = 0; k0 < D_; k0 += 64) {
        bf16x8 af[2][2], bfm[2][2];
#pragma unroll
        for (int hf = 0; hf < 2; ++hf) {
#pragma unroll
            for (int ms = 0; ms < 2; ++ms)
                af[ms][hf] = *(const bf16x8*)(A + (size_t)(mbase + ms * 16 + lr) * D_ +
                                              k0 + hf * 32 + lg * 8);
#pragma unroll
            for (int ns = 0; ns < 2; ++ns)
                bfm[ns][hf] = *(const bf16x8*)(Wm + (size_t)(nbase + ns * 16 + lr) * D_ +
                                               k0 + hf * 32 + lg * 8);
        }
#pragma unroll
        for (int hf = 0; hf < 2; ++hf)
#pragma unroll
            for (int ms = 0; ms < 2; ++ms)
#pragma unroll
                for (int ns = 0; ns < 2; ++ns)
                    acc[ms][ns] = __builtin_amdgcn_mfma_f32_16x16x32_bf16(
                        af[ms][hf], bfm[ns][hf], acc[ms][ns], 0, 0, 0);
    }

#pragma unroll
    for (int ms = 0; ms < 2; ++ms) {
#pragma unroll
        for (int ns = 0; ns < 2; ++ns) {
#pragma unroll
            for (int r = 0; r < 4; ++r) {
                const int row = mbase + ms * 16 + lg * 4 + r;
                const int col = nbase + ns * 16 + lr;
                float v = acc[ms][ns][r];
                if (z == 0) {
                    v += bq[col];
                    const int b = row >> 10, tok = row & 1023;
                    const int h = col / HD_, hd = col - h * HD_;
                    qp[((size_t)((b * H_ + h) * N_ + tok) << 6) + hd] = f2bf(v);
                } else if (z == 1) {
                    const int b = row >> 10, tok = row & 1023;
                    const int h = col / HD_, hd = col - h * HD_;
                    kp[((size_t)((b * H_ + h) * N_ + tok) << 6) + hd] = f2bf(v);
                } else if (z == 3) {
                    g[(size_t)row * D_ + col] = 1.f / (1.f + __expf(-v));
                } else {
                    const int b = col >> 10, tok = col & 1023;
                    const int h = row / HD_, hd = row - h * HD_;
                    vT[((size_t)((b * H_ + h) * HD_ + hd) << 10) + tok] = f2bf(v);
                }
            }
        }
    }
}

// ---------------------------------------------------------------------------
// stage one 64-row edge tile into LDS via global_load_lds (XOR-pre-swizzled
// global source, linear LDS dest; read side applies the same XOR).
// ---------------------------------------------------------------------------
__device__ __forceinline__ void stage_tile(const float* __restrict__ edge,
                                           size_t row0, float* etbuf,
                                           int w, int lane)
{
#pragma unroll
    for (int u = 0; u < 8; ++u) {
        const int row = w * 16 + u * 2 + (lane >> 5);
        const int sl = (lane & 31) ^ (row & 7);
        const float* src = edge + (row0 + row) * E_ + (sl << 2);
        float* dst = etbuf + (w * 16 + u * 2) * E_;
        __builtin_amdgcn_global_load_lds(
            (const __attribute__((address_space(1))) void*)src,
            (__attribute__((address_space(3))) void*)dst, 16, 0, 0);
    }
}

// ---------------------------------------------------------------------------
// Kernel 2: pair bias — global_load_lds double-buffered persistent stream.
// (unchanged from R8; launched TWICE this round for dur_us attribution)
// ---------------------------------------------------------------------------
__global__ __launch_bounds__(256, 2) void bias_kernel(
    const float* __restrict__ edge, const float* __restrict__ lng,
    const float* __restrict__ lnb, const float* __restrict__ Wz,
    const int* __restrict__ mask, unsigned short* __restrict__ bias)
{
    const int tid = threadIdx.x;
    const int lane = tid & 63;
    const int w = tid >> 6;
    const int lr = lane & 15, lg = lane >> 4;

    __shared__ __align__(16) float et[2][64 * E_];

    bf16x8 wzf[4];
#pragma unroll
    for (int ks = 0; ks < 4; ++ks)
#pragma unroll
        for (int e = 0; e < 8; ++e)
            wzf[ks][e] = (short)f2bf(Wz[(ks * 32 + lg * 8 + e) * H_ + lr]);

    size_t t = blockIdx.x;
    stage_tile(edge, t * 64, et[0], w, lane);
    __syncthreads();

    for (int it = 0; it < 16; ++it) {
        float* cbuf = et[it & 1];
        float* nbuf = et[(it & 1) ^ 1];
        if (it < 15) stage_tile(edge, (t + 2048) * 64, nbuf, w, lane);

        const int row = w * 16 + lr;
        const int rx = row & 7;
        const float* xr = cbuf + row * E_;
        float x[4][8];
        float s = 0.f, sq = 0.f;
#pragma unroll
        for (int ks = 0; ks < 4; ++ks) {
            const int s0 = ks * 8 + lg * 2;
            const float4 a = *(const float4*)(xr + ((s0 ^ rx) << 2));
            const float4 bb = *(const float4*)(xr + (((s0 + 1) ^ rx) << 2));
            x[ks][0] = a.x; x[ks][1] = a.y; x[ks][2] = a.z; x[ks][3] = a.w;
            x[ks][4] = bb.x; x[ks][5] = bb.y; x[ks][6] = bb.z; x[ks][7] = bb.w;
#pragma unroll
            for (int e = 0; e < 8; ++e) { s += x[ks][e]; sq = fmaf(x[ks][e], x[ks][e], sq); }
        }
        s  += __shfl_xor(s, 16);  s  += __shfl_xor(s, 32);
        sq += __shfl_xor(sq, 16); sq += __shfl_xor(sq, 32);
        const float mean = s * (1.f / 128.f);
        const float var = sq * (1.f / 128.f) - mean * mean;
        const float rs = rsqrtf(var + 1e-5f);
        const float c0 = -mean * rs;

        f32x4 acc = {};
#pragma unroll
        for (int ks = 0; ks < 4; ++ks) {
            bf16x8 af;
#pragma unroll
            for (int e = 0; e < 8; ++e) {
                const int ee = ks * 32 + lg * 8 + e;
                const float zn = fmaf(fmaf(x[ks][e], rs, c0), lng[ee], lnb[ee]);
                af[e] = (short)f2bf(zn);
            }
            acc = __builtin_amdgcn_mfma_f32_16x16x32_bf16(af, wzf[ks], acc, 0, 0, 0);
        }

        const int b = (int)(t >> 14);
        const int i = (int)((t >> 4) & 1023);
        const int j = (int)((t & 15) << 6) + w * 16 + lg * 4;
        const int4 mv = *(const int4*)(mask + b * N_ + j);
        const int* mvp = (const int*)&mv;
        ushort4 pk;
        pk.x = f2bf(acc[0] + (1.f - (float)mvp[0]) * (-1.0e6f));
        pk.y = f2bf(acc[1] + (1.f - (float)mvp[1]) * (-1.0e6f));
        pk.z = f2bf(acc[2] + (1.f - (float)mvp[2]) * (-1.0e6f));
        pk.w = f2bf(acc[3] + (1.f - (float)mvp[3]) * (-1.0e6f));
        *(ushort4*)(bias + (((size_t)((b * H_ + lr) * N_ + i)) << 10) + j) = pk;

        __syncthreads();
        t += 2048;
    }
}

// ---------------------------------------------------------------------------
// Kernel 3: attention (R8 math), ATTN_REPS idempotent loop for rocprof.
// ---------------------------------------------------------------------------
__global__ __launch_bounds__(256) void attn_kernel(
    const unsigned short* __restrict__ qp, const unsigned short* __restrict__ kp,
    const unsigned short* __restrict__ vT, const unsigned short* __restrict__ bias,
    const float* __restrict__ g,
    unsigned short* __restrict__ Xhi, unsigned short* __restrict__ Xlo)
{
    const int tid = threadIdx.x;
    const int w = tid >> 6;
    const int lane = tid & 63;
    const int lr = lane & 15, lg = lane >> 4;
    const int bh = blockIdx.x >> 6;
    const int it = blockIdx.x & 63;
    const int b = bh >> 4;
    const int h = bh & 15;
    const int i0 = it * 16;
    const float scale = 0.14433756729740643f;

    __shared__ unsigned short pt[4][16][40];
    __shared__ float comb[3][64][13];

    bf16x8 qf0, qf1;
    {
        const unsigned short* qb = qp + (((size_t)bh * N_ + i0 + lr) << 6) + lg * 8;
        qf0 = *(const bf16x8*)qb;
        qf1 = *(const bf16x8*)(qb + 32);
    }
    const unsigned short* biasrow =
        bias + ((size_t)bh << 20) + ((size_t)(i0 + lr) << 10);
    const int jlo = w * 256;

    for (int rep = 0; rep < ATTN_REPS; ++rep) {
        __syncthreads();   // protect comb reuse across reps
        float li = 0.f;
        f32x4 ov[3] = {};

        for (int j0 = jlo; j0 < jlo + 256; j0 += 32) {
#pragma unroll
            for (int s = 0; s < 2; ++s) {
                const unsigned short* kb =
                    kp + (((size_t)bh * N_ + j0 + s * 16 + lr) << 6) + lg * 8;
                bf16x8 k0 = *(const bf16x8*)kb;
                bf16x8 k1 = *(const bf16x8*)(kb + 32);
                f32x4 tacc = {};
                tacc = __builtin_amdgcn_mfma_f32_16x16x32_bf16(k0, qf0, tacc, 0, 0, 0);
                tacc = __builtin_amdgcn_mfma_f32_16x16x32_bf16(k1, qf1, tacc, 0, 0, 0);
                const ushort4 bv = *(const ushort4*)(biasrow + j0 + s * 16 + lg * 4);
                const unsigned short* bvp = (const unsigned short*)&bv;
                float p[4];
#pragma unroll
                for (int r = 0; r < 4; ++r) {
                    p[r] = __expf(fmaf(tacc[r], scale, bf2f(bvp[r])));
                    li += p[r];
                }
                ushort4 pk;
                pk.x = f2bf(p[0]); pk.y = f2bf(p[1]);
                pk.z = f2bf(p[2]); pk.w = f2bf(p[3]);
                *(ushort4*)&pt[w][lr][s * 16 + lg * 4] = pk;
            }
            bf16x8 pa = *(const bf16x8*)&pt[w][lr][lg * 8];
#pragma unroll
            for (int v = 0; v < 3; ++v) {
                const unsigned short* vb =
                    vT + (((size_t)(bh * HD_ + v * 16 + lr)) << 10) + j0 + lg * 8;
                bf16x8 vf = *(const bf16x8*)vb;
                ov[v] = __builtin_amdgcn_mfma_f32_16x16x32_bf16(pa, vf, ov[v], 0, 0, 0);
            }
        }

        if (w > 0) {
            float* cb = &comb[w - 1][lane][0];
#pragma unroll
            for (int v = 0; v < 3; ++v)
#pragma unroll
                for (int r = 0; r < 4; ++r) cb[v * 4 + r] = ov[v][r];
            cb[12] = li;
        }
        __syncthreads();
        if (w == 0) {
#pragma unroll
            for (int s = 0; s < 3; ++s) {
                const float* cb = &comb[s][lane][0];
#pragma unroll
                for (int v = 0; v < 3; ++v)
#pragma unroll
                    for (int r = 0; r < 4; ++r) ov[v][r] += cb[v * 4 + r];
                li += cb[12];
            }
            li += __shfl_xor(li, 16);
            li += __shfl_xor(li, 32);
            float lired[4];
#pragma unroll
            for (int r = 0; r < 4; ++r) lired[r] = __shfl(li, lg * 4 + r);

#pragma unroll
            for (int v = 0; v < 3; ++v) {
#pragma unroll
                for (int r = 0; r < 4; ++r) {
                    const size_t row = (size_t)(b * N_ + i0 + lg * 4 + r);
                    const int col = h * HD_ + v * 16 + lr;
                    const float xv = g[row * D_ + col] * (ov[v][r] / lired[r]);
                    const unsigned short hi = f2bf(xv);
                    const size_t off = row * D_ + col;
                    Xhi[off] = hi;
                    Xlo[off] = f2bf(xv - bf2f(hi));
                }
            }
        }
    }
}

// ---------------------------------------------------------------------------
// Kernel 4: out = X @ Wo.T via split-bf16
// ---------------------------------------------------------------------------
__global__ __launch_bounds__(256) void out_gemm(
    const unsigned short* __restrict__ Xhi, const unsigned short* __restrict__ Xlo,
    const unsigned short* __restrict__ Whi, const unsigned short* __restrict__ Wlo,
    float* __restrict__ out)
{
    const int lane = threadIdx.x & 63;
    const int w = threadIdx.x >> 6;
    const int wm = w >> 1, wn = w & 1;
    const int lr = lane & 15, lg = lane >> 4;
    const int mbase = blockIdx.x * 64 + wm * 32;
    const int nbase = blockIdx.y * 64 + wn * 32;

    f32x4 acc[2][2] = {};
    for (int k0 = 0; k0 < D_; k0 += 32) {
        bf16x8 ah[2], al[2], bh[2], bl[2];
#pragma unroll
        for (int ms = 0; ms < 2; ++ms) {
            const size_t off = (size_t)(mbase + ms * 16 + lr) * D_ + k0 + lg * 8;
            ah[ms] = *(const bf16x8*)(Xhi + off);
            al[ms] = *(const bf16x8*)(Xlo + off);
        }
#pragma unroll
        for (int ns = 0; ns < 2; ++ns) {
            const size_t off = (size_t)(nbase + ns * 16 + lr) * D_ + k0 + lg * 8;
            bh[ns] = *(const bf16x8*)(Whi + off);
            bl[ns] = *(const bf16x8*)(Wlo + off);
        }
#pragma unroll
        for (int ms = 0; ms < 2; ++ms)
#pragma unroll
            for (int ns = 0; ns < 2; ++ns) {
                acc[ms][ns] = __builtin_amdgcn_mfma_f32_16x16x32_bf16(ah[ms], bh[ns], acc[ms][ns], 0, 0, 0);
                acc[ms][ns] = __builtin_amdgcn_mfma_f32_16x16x32_bf16(ah[ms], bl[ns], acc[ms][ns], 0, 0, 0);
                acc[ms][ns] = __builtin_amdgcn_mfma_f32_16x16x32_bf16(al[ms], bh[ns], acc[ms][ns], 0, 0, 0);
            }
    }
#pragma unroll
    for (int ms = 0; ms < 2; ++ms)
#pragma unroll
        for (int ns = 0; ns < 2; ++ns)
#pragma unroll
            for (int r = 0; r < 4; ++r)
                out[(size_t)(mbase + ms * 16 + lg * 4 + r) * D_ + nbase + ns * 16 + lr] =
                    acc[ms][ns][r];
}

// ---------------------------------------------------------------------------
extern "C" void kernel_launch(void* const* d_in, const int* in_sizes, int n_in,
                              void* d_out, int out_size, void* d_ws, size_t ws_size,
                              hipStream_t stream) {
    const float* node = (const float*)d_in[0];
    const float* edge = (const float*)d_in[1];
    const int*   mask = (const int*)d_in[2];
    const float* kin  = (const float*)d_in[3];
    const float* Wq   = (const float*)d_in[4];
    const float* bq   = (const float*)d_in[5];
    const float* Wk   = (const float*)d_in[6];
    const float* Wv   = (const float*)d_in[7];
    const float* Wg   = (const float*)d_in[8];
    const float* lng  = (const float*)d_in[9];
    const float* lnb  = (const float*)d_in[10];
    const float* Wz   = (const float*)d_in[11];
    const float* Wo   = (const float*)d_in[12];
    float* out = (float*)d_out;

    char* ws = (char*)d_ws;
    const size_t qk_bytes = (size_t)B_ * H_ * N_ * HDP_ * 2;
    unsigned short* qp = (unsigned short*)ws;   ws += qk_bytes;
    unsigned short* kp = (unsigned short*)ws;   ws += qk_bytes;
    unsigned short* vT = (unsigned short*)ws;   ws += (size_t)B_ * H_ * HD_ * N_ * 2;
    float* gbuf = (float*)ws;                   ws += (size_t)B_ * N_ * D_ * 4;
    unsigned short* bias = (unsigned short*)ws; ws += (size_t)B_ * H_ * N_ * N_ * 2;
    unsigned short* Xhi = (unsigned short*)ws;  ws += (size_t)B_ * N_ * D_ * 2;
    unsigned short* Xlo = (unsigned short*)ws;  ws += (size_t)B_ * N_ * D_ * 2;
    unsigned short* Whi = (unsigned short*)ws;  ws += (size_t)D_ * D_ * 2;
    unsigned short* Wlo = (unsigned short*)ws;  ws += (size_t)D_ * D_ * 2;
    unsigned short* nb  = (unsigned short*)ws;  ws += (size_t)B_ * N_ * D_ * 2;
    unsigned short* kb  = (unsigned short*)ws;  ws += (size_t)B_ * N_ * D_ * 2;
    unsigned short* WqB = (unsigned short*)ws;  ws += (size_t)D_ * D_ * 2;
    unsigned short* WkB = (unsigned short*)ws;  ws += (size_t)D_ * D_ * 2;
    unsigned short* WvB = (unsigned short*)ws;  ws += (size_t)D_ * D_ * 2;
    unsigned short* WgB = (unsigned short*)ws;  ws += (size_t)D_ * D_ * 2;

    conv_prep<<<dim3(1536, 8), 256, 0, stream>>>(
        node, kin, Wq, Wk, Wv, Wg, Wo,
        nb, kb, WqB, WkB, WvB, WgB, Whi, Wlo, qp, kp);
    proj_kernel<<<dim3(32, 12, 4), 256, 0, stream>>>(
        nb, kb, WqB, WkB, WvB, WgB, bq, qp, kp, vT, gbuf);
    bias_kernel<<<dim3(2048), 256, 0, stream>>>(edge, lng, lnb, Wz, mask, bias);
    bias_kernel<<<dim3(2048), 256, 0, stream>>>(edge, lng, lnb, Wz, mask, bias);
    attn_kernel<<<dim3(2048), 256, 0, stream>>>(qp, kp, vT, bias, gbuf, Xhi, Xlo);
    out_gemm<<<dim3(32, 12), 256, 0, stream>>>(Xhi, Xlo, Whi, Wlo, out);
}

// Round 10
// 405.432 us; speedup vs baseline: 3.9139x; 3.9139x over previous
//
#include <hip/hip_runtime.h>
#include <hip/hip_bf16.h>

#define B_ 2
#define N_ 1024
#define D_ 768
#define E_ 128
#define H_ 16
#define HD_ 48
#define HDP_ 64

typedef short bf16x8 __attribute__((ext_vector_type(8)));
typedef float f32x4 __attribute__((ext_vector_type(4)));

__device__ __forceinline__ unsigned short f2bf(float f) {
    __hip_bfloat16 h = __float2bfloat16(f);
    return *reinterpret_cast<unsigned short*>(&h);
}
__device__ __forceinline__ float bf2f(unsigned short s) {
    return __uint_as_float(((unsigned int)s) << 16);
}

// ---------------------------------------------------------------------------
// Kernel 0: conv_prep — all input conversions in one coalesced pass.
// ---------------------------------------------------------------------------
__global__ __launch_bounds__(256) void conv_prep(
    const float* __restrict__ node, const float* __restrict__ kin,
    const float* __restrict__ Wq, const float* __restrict__ Wk,
    const float* __restrict__ Wv, const float* __restrict__ Wg,
    const float* __restrict__ Wo,
    unsigned short* __restrict__ nb, unsigned short* __restrict__ kb,
    unsigned short* __restrict__ WqB, unsigned short* __restrict__ WkB,
    unsigned short* __restrict__ WvB, unsigned short* __restrict__ WgB,
    unsigned short* __restrict__ Whi, unsigned short* __restrict__ Wlo,
    unsigned short* __restrict__ qp, unsigned short* __restrict__ kp)
{
    const int y = blockIdx.y;
    const int t = blockIdx.x * 256 + threadIdx.x;
    if (y < 6) {
        const int n = (y < 2) ? (B_ * N_ * D_) : (D_ * D_);
        const int i4 = t * 4;
        if (i4 < n) {
            const float* s = (y == 0) ? node : (y == 1) ? kin :
                             (y == 2) ? Wq : (y == 3) ? Wk : (y == 4) ? Wv : Wg;
            unsigned short* d = (y == 0) ? nb : (y == 1) ? kb :
                                (y == 2) ? WqB : (y == 3) ? WkB : (y == 4) ? WvB : WgB;
            const float4 v = *(const float4*)(s + i4);
            ushort4 o;
            o.x = f2bf(v.x); o.y = f2bf(v.y); o.z = f2bf(v.z); o.w = f2bf(v.w);
            *(ushort4*)(d + i4) = o;
        }
    } else if (y == 6) {
        const int i4 = t * 4;
        if (i4 < D_ * D_) {
            const float4 v = *(const float4*)(Wo + i4);
            ushort4 hi, lo;
            hi.x = f2bf(v.x); lo.x = f2bf(v.x - bf2f(hi.x));
            hi.y = f2bf(v.y); lo.y = f2bf(v.y - bf2f(hi.y));
            hi.z = f2bf(v.z); lo.z = f2bf(v.z - bf2f(hi.z));
            hi.w = f2bf(v.w); lo.w = f2bf(v.w - bf2f(hi.w));
            *(ushort4*)(Whi + i4) = hi;
            *(ushort4*)(Wlo + i4) = lo;
        }
    } else {
        if (t < B_ * H_ * N_ * 2) {
            const int row = t >> 1, half = t & 1;
            uint4 z = {0u, 0u, 0u, 0u};
            *(uint4*)(qp + ((size_t)row << 6) + 48 + half * 8) = z;
            *(uint4*)(kp + ((size_t)row << 6) + 48 + half * 8) = z;
        }
    }
}

// ---------------------------------------------------------------------------
// Kernel 1: merged projections.  pair=0: A=node -> {q (W=Wq), g (W=Wg)}
// pair=1: A=kin -> {k = kin@Wk.T ; v^T = Wv@kin^T}.  Key trick: on gfx950 the
// A-frag and B-frag lane layouts are identical, so the kin fragment loaded
// once serves as A for the k-GEMM and as B for the v-GEMM.
// ---------------------------------------------------------------------------
__global__ __launch_bounds__(256) void proj2_kernel(
    const unsigned short* __restrict__ nb, const unsigned short* __restrict__ kb,
    const unsigned short* __restrict__ WqB, const unsigned short* __restrict__ WkB,
    const unsigned short* __restrict__ WvB, const unsigned short* __restrict__ WgB,
    const float* __restrict__ bq,
    unsigned short* __restrict__ qp, unsigned short* __restrict__ kp,
    unsigned short* __restrict__ vT, float* __restrict__ g)
{
    const int pair = blockIdx.z;
    const int lane = threadIdx.x & 63;
    const int w = threadIdx.x >> 6;
    const int wm = w >> 1, wn = w & 1;
    const int lr = lane & 15, lg = lane >> 4;
    const int mbase = blockIdx.x * 64 + wm * 32;   // token rows (2048)
    const int nbase = blockIdx.y * 64 + wn * 32;   // d cols (768)

    const unsigned short* A  = pair ? kb  : nb;
    const unsigned short* W1 = pair ? WkB : WqB;
    const unsigned short* W2 = pair ? WvB : WgB;

    f32x4 acc1[2][2] = {};   // pair0: q ; pair1: k     (row=tok, col=d)
    f32x4 acc2[2][2] = {};   // pair0: g (row=tok,col=d); pair1: v (row=d,col=tok)

    for (int k0 = 0; k0 < D_; k0 += 64) {
        bf16x8 af[2][2], w1f[2][2], w2f[2][2];
#pragma unroll
        for (int hf = 0; hf < 2; ++hf) {
#pragma unroll
            for (int ms = 0; ms < 2; ++ms)
                af[ms][hf] = *(const bf16x8*)(A + (size_t)(mbase + ms * 16 + lr) * D_ +
                                              k0 + hf * 32 + lg * 8);
#pragma unroll
            for (int ns = 0; ns < 2; ++ns) {
                const size_t off = (size_t)(nbase + ns * 16 + lr) * D_ + k0 + hf * 32 + lg * 8;
                w1f[ns][hf] = *(const bf16x8*)(W1 + off);
                w2f[ns][hf] = *(const bf16x8*)(W2 + off);
            }
        }
#pragma unroll
        for (int hf = 0; hf < 2; ++hf)
#pragma unroll
            for (int ms = 0; ms < 2; ++ms)
#pragma unroll
                for (int ns = 0; ns < 2; ++ns) {
                    acc1[ms][ns] = __builtin_amdgcn_mfma_f32_16x16x32_bf16(
                        af[ms][hf], w1f[ns][hf], acc1[ms][ns], 0, 0, 0);
                    if (pair == 0)
                        acc2[ms][ns] = __builtin_amdgcn_mfma_f32_16x16x32_bf16(
                            af[ms][hf], w2f[ns][hf], acc2[ms][ns], 0, 0, 0);
                    else   // v: A = Wv rows (d), B = kin frag (cols tok)
                        acc2[ns][ms] = __builtin_amdgcn_mfma_f32_16x16x32_bf16(
                            w2f[ns][hf], af[ms][hf], acc2[ns][ms], 0, 0, 0);
                }
    }

#pragma unroll
    for (int ms = 0; ms < 2; ++ms) {
#pragma unroll
        for (int ns = 0; ns < 2; ++ns) {
#pragma unroll
            for (int r = 0; r < 4; ++r) {
                // acc1 (q or k): row = token, col = d
                {
                    const int tokrow = mbase + ms * 16 + lg * 4 + r;
                    const int dcol = nbase + ns * 16 + lr;
                    const int b = tokrow >> 10, tok = tokrow & 1023;
                    const int h = dcol / HD_, hd = dcol - h * HD_;
                    float v = acc1[ms][ns][r];
                    if (pair == 0) v += bq[dcol];
                    unsigned short* dst = (pair == 0) ? qp : kp;
                    dst[((size_t)((b * H_ + h) * N_ + tok) << 6) + hd] = f2bf(v);
                }
                if (pair == 0) {
                    // g: row = token, col = d
                    const int tokrow = mbase + ms * 16 + lg * 4 + r;
                    const int dcol = nbase + ns * 16 + lr;
                    g[(size_t)tokrow * D_ + dcol] =
                        1.f / (1.f + __expf(-acc2[ms][ns][r]));
                } else {
                    // v: acc2[ns][ms] -> row = d, col = token
                    const int drow = nbase + ns * 16 + lg * 4 + r;
                    const int tokcol = mbase + ms * 16 + lr;
                    const int b = tokcol >> 10, tok = tokcol & 1023;
                    const int h = drow / HD_, hd = drow - h * HD_;
                    vT[((size_t)((b * H_ + h) * HD_ + hd) << 10) + tok] =
                        f2bf(acc2[ns][ms][r]);
                }
            }
        }
    }
}

// ---------------------------------------------------------------------------
// stage one 64-row edge tile into LDS via global_load_lds (XOR-pre-swizzled
// global source, linear LDS dest; read side applies the same XOR).
// ---------------------------------------------------------------------------
__device__ __forceinline__ void stage_tile(const float* __restrict__ edge,
                                           size_t row0, float* etbuf,
                                           int w, int lane)
{
#pragma unroll
    for (int u = 0; u < 8; ++u) {
        const int row = w * 16 + u * 2 + (lane >> 5);
        const int sl = (lane & 31) ^ (row & 7);
        const float* src = edge + (row0 + row) * E_ + (sl << 2);
        float* dst = etbuf + (w * 16 + u * 2) * E_;
        __builtin_amdgcn_global_load_lds(
            (const __attribute__((address_space(1))) void*)src,
            (__attribute__((address_space(3))) void*)dst, 16, 0, 0);
    }
}

// ---------------------------------------------------------------------------
// Kernel 2: pair bias — global_load_lds double-buffered persistent stream.
// Measured at ~157us ~= pure-read roofline for the 1.07GB edge tensor.
// ---------------------------------------------------------------------------
__global__ __launch_bounds__(256, 2) void bias_kernel(
    const float* __restrict__ edge, const float* __restrict__ lng,
    const float* __restrict__ lnb, const float* __restrict__ Wz,
    const int* __restrict__ mask, unsigned short* __restrict__ bias)
{
    const int tid = threadIdx.x;
    const int lane = tid & 63;
    const int w = tid >> 6;
    const int lr = lane & 15, lg = lane >> 4;

    __shared__ __align__(16) float et[2][64 * E_];

    bf16x8 wzf[4];
#pragma unroll
    for (int ks = 0; ks < 4; ++ks)
#pragma unroll
        for (int e = 0; e < 8; ++e)
            wzf[ks][e] = (short)f2bf(Wz[(ks * 32 + lg * 8 + e) * H_ + lr]);

    size_t t = blockIdx.x;
    stage_tile(edge, t * 64, et[0], w, lane);
    __syncthreads();

    for (int it = 0; it < 16; ++it) {
        float* cbuf = et[it & 1];
        float* nbuf = et[(it & 1) ^ 1];
        if (it < 15) stage_tile(edge, (t + 2048) * 64, nbuf, w, lane);

        const int row = w * 16 + lr;
        const int rx = row & 7;
        const float* xr = cbuf + row * E_;
        float x[4][8];
        float s = 0.f, sq = 0.f;
#pragma unroll
        for (int ks = 0; ks < 4; ++ks) {
            const int s0 = ks * 8 + lg * 2;
            const float4 a = *(const float4*)(xr + ((s0 ^ rx) << 2));
            const float4 bb = *(const float4*)(xr + (((s0 + 1) ^ rx) << 2));
            x[ks][0] = a.x; x[ks][1] = a.y; x[ks][2] = a.z; x[ks][3] = a.w;
            x[ks][4] = bb.x; x[ks][5] = bb.y; x[ks][6] = bb.z; x[ks][7] = bb.w;
#pragma unroll
            for (int e = 0; e < 8; ++e) { s += x[ks][e]; sq = fmaf(x[ks][e], x[ks][e], sq); }
        }
        s  += __shfl_xor(s, 16);  s  += __shfl_xor(s, 32);
        sq += __shfl_xor(sq, 16); sq += __shfl_xor(sq, 32);
        const float mean = s * (1.f / 128.f);
        const float var = sq * (1.f / 128.f) - mean * mean;
        const float rs = rsqrtf(var + 1e-5f);
        const float c0 = -mean * rs;

        f32x4 acc = {};
#pragma unroll
        for (int ks = 0; ks < 4; ++ks) {
            bf16x8 af;
#pragma unroll
            for (int e = 0; e < 8; ++e) {
                const int ee = ks * 32 + lg * 8 + e;
                const float zn = fmaf(fmaf(x[ks][e], rs, c0), lng[ee], lnb[ee]);
                af[e] = (short)f2bf(zn);
            }
            acc = __builtin_amdgcn_mfma_f32_16x16x32_bf16(af, wzf[ks], acc, 0, 0, 0);
        }

        const int b = (int)(t >> 14);
        const int i = (int)((t >> 4) & 1023);
        const int j = (int)((t & 15) << 6) + w * 16 + lg * 4;
        const int4 mv = *(const int4*)(mask + b * N_ + j);
        const int* mvp = (const int*)&mv;
        ushort4 pk;
        pk.x = f2bf(acc[0] + (1.f - (float)mvp[0]) * (-1.0e6f));
        pk.y = f2bf(acc[1] + (1.f - (float)mvp[1]) * (-1.0e6f));
        pk.z = f2bf(acc[2] + (1.f - (float)mvp[2]) * (-1.0e6f));
        pk.w = f2bf(acc[3] + (1.f - (float)mvp[3]) * (-1.0e6f));
        *(ushort4*)(bias + (((size_t)((b * H_ + lr) * N_ + i)) << 10) + j) = pk;

        __syncthreads();
        t += 2048;
    }
}

// ---------------------------------------------------------------------------
// Kernel 3: attention (single-pass R8 form).
// ---------------------------------------------------------------------------
__global__ __launch_bounds__(256) void attn_kernel(
    const unsigned short* __restrict__ qp, const unsigned short* __restrict__ kp,
    const unsigned short* __restrict__ vT, const unsigned short* __restrict__ bias,
    const float* __restrict__ g,
    unsigned short* __restrict__ Xhi, unsigned short* __restrict__ Xlo)
{
    const int tid = threadIdx.x;
    const int w = tid >> 6;
    const int lane = tid & 63;
    const int lr = lane & 15, lg = lane >> 4;
    const int bh = blockIdx.x >> 6;
    const int it = blockIdx.x & 63;
    const int b = bh >> 4;
    const int h = bh & 15;
    const int i0 = it * 16;
    const float scale = 0.14433756729740643f;

    __shared__ unsigned short pt[4][16][40];
    __shared__ float comb[3][64][13];

    bf16x8 qf0, qf1;
    {
        const unsigned short* qb = qp + (((size_t)bh * N_ + i0 + lr) << 6) + lg * 8;
        qf0 = *(const bf16x8*)qb;
        qf1 = *(const bf16x8*)(qb + 32);
    }

    float li = 0.f;
    f32x4 ov[3] = {};
    const unsigned short* biasrow =
        bias + ((size_t)bh << 20) + ((size_t)(i0 + lr) << 10);

    const int jlo = w * 256;
    for (int j0 = jlo; j0 < jlo + 256; j0 += 32) {
#pragma unroll
        for (int s = 0; s < 2; ++s) {
            const unsigned short* kb =
                kp + (((size_t)bh * N_ + j0 + s * 16 + lr) << 6) + lg * 8;
            bf16x8 k0 = *(const bf16x8*)kb;
            bf16x8 k1 = *(const bf16x8*)(kb + 32);
            f32x4 tacc = {};
            tacc = __builtin_amdgcn_mfma_f32_16x16x32_bf16(k0, qf0, tacc, 0, 0, 0);
            tacc = __builtin_amdgcn_mfma_f32_16x16x32_bf16(k1, qf1, tacc, 0, 0, 0);
            const ushort4 bv = *(const ushort4*)(biasrow + j0 + s * 16 + lg * 4);
            const unsigned short* bvp = (const unsigned short*)&bv;
            float p[4];
#pragma unroll
            for (int r = 0; r < 4; ++r) {
                p[r] = __expf(fmaf(tacc[r], scale, bf2f(bvp[r])));
                li += p[r];
            }
            ushort4 pk;
            pk.x = f2bf(p[0]); pk.y = f2bf(p[1]);
            pk.z = f2bf(p[2]); pk.w = f2bf(p[3]);
            *(ushort4*)&pt[w][lr][s * 16 + lg * 4] = pk;
        }
        bf16x8 pa = *(const bf16x8*)&pt[w][lr][lg * 8];
#pragma unroll
        for (int v = 0; v < 3; ++v) {
            const unsigned short* vb =
                vT + (((size_t)(bh * HD_ + v * 16 + lr)) << 10) + j0 + lg * 8;
            bf16x8 vf = *(const bf16x8*)vb;
            ov[v] = __builtin_amdgcn_mfma_f32_16x16x32_bf16(pa, vf, ov[v], 0, 0, 0);
        }
    }

    if (w > 0) {
        float* cb = &comb[w - 1][lane][0];
#pragma unroll
        for (int v = 0; v < 3; ++v)
#pragma unroll
            for (int r = 0; r < 4; ++r) cb[v * 4 + r] = ov[v][r];
        cb[12] = li;
    }
    __syncthreads();
    if (w == 0) {
#pragma unroll
        for (int s = 0; s < 3; ++s) {
            const float* cb = &comb[s][lane][0];
#pragma unroll
            for (int v = 0; v < 3; ++v)
#pragma unroll
                for (int r = 0; r < 4; ++r) ov[v][r] += cb[v * 4 + r];
            li += cb[12];
        }
        li += __shfl_xor(li, 16);
        li += __shfl_xor(li, 32);
        float lired[4];
#pragma unroll
        for (int r = 0; r < 4; ++r) lired[r] = __shfl(li, lg * 4 + r);

#pragma unroll
        for (int v = 0; v < 3; ++v) {
#pragma unroll
            for (int r = 0; r < 4; ++r) {
                const size_t row = (size_t)(b * N_ + i0 + lg * 4 + r);
                const int col = h * HD_ + v * 16 + lr;
                const float xv = g[row * D_ + col] * (ov[v][r] / lired[r]);
                const unsigned short hi = f2bf(xv);
                const size_t off = row * D_ + col;
                Xhi[off] = hi;
                Xlo[off] = f2bf(xv - bf2f(hi));
            }
        }
    }
}

// ---------------------------------------------------------------------------
// Kernel 4: out = X @ Wo.T via split-bf16, SPLIT-K x2 (atomicAdd combine;
// exactly 2 commutative fp32 adds per element -> bit-deterministic).
// ---------------------------------------------------------------------------
__global__ __launch_bounds__(256) void out_gemm2(
    const unsigned short* __restrict__ Xhi, const unsigned short* __restrict__ Xlo,
    const unsigned short* __restrict__ Whi, const unsigned short* __restrict__ Wlo,
    float* __restrict__ out)
{
    const int kz = blockIdx.z;
    const int lane = threadIdx.x & 63;
    const int w = threadIdx.x >> 6;
    const int wm = w >> 1, wn = w & 1;
    const int lr = lane & 15, lg = lane >> 4;
    const int mbase = blockIdx.x * 64 + wm * 32;
    const int nbase = blockIdx.y * 64 + wn * 32;

    f32x4 acc[2][2] = {};
    for (int k0 = kz * 384; k0 < kz * 384 + 384; k0 += 32) {
        bf16x8 ah[2], al[2], bh[2], bl[2];
#pragma unroll
        for (int ms = 0; ms < 2; ++ms) {
            const size_t off = (size_t)(mbase + ms * 16 + lr) * D_ + k0 + lg * 8;
            ah[ms] = *(const bf16x8*)(Xhi + off);
            al[ms] = *(const bf16x8*)(Xlo + off);
        }
#pragma unroll
        for (int ns = 0; ns < 2; ++ns) {
            const size_t off = (size_t)(nbase + ns * 16 + lr) * D_ + k0 + lg * 8;
            bh[ns] = *(const bf16x8*)(Whi + off);
            bl[ns] = *(const bf16x8*)(Wlo + off);
        }
#pragma unroll
        for (int ms = 0; ms < 2; ++ms)
#pragma unroll
            for (int ns = 0; ns < 2; ++ns) {
                acc[ms][ns] = __builtin_amdgcn_mfma_f32_16x16x32_bf16(ah[ms], bh[ns], acc[ms][ns], 0, 0, 0);
                acc[ms][ns] = __builtin_amdgcn_mfma_f32_16x16x32_bf16(ah[ms], bl[ns], acc[ms][ns], 0, 0, 0);
                acc[ms][ns] = __builtin_amdgcn_mfma_f32_16x16x32_bf16(al[ms], bh[ns], acc[ms][ns], 0, 0, 0);
            }
    }
#pragma unroll
    for (int ms = 0; ms < 2; ++ms)
#pragma unroll
        for (int ns = 0; ns < 2; ++ns)
#pragma unroll
            for (int r = 0; r < 4; ++r)
                atomicAdd(&out[(size_t)(mbase + ms * 16 + lg * 4 + r) * D_ +
                               nbase + ns * 16 + lr],
                          acc[ms][ns][r]);
}

// ---------------------------------------------------------------------------
extern "C" void kernel_launch(void* const* d_in, const int* in_sizes, int n_in,
                              void* d_out, int out_size, void* d_ws, size_t ws_size,
                              hipStream_t stream) {
    const float* node = (const float*)d_in[0];
    const float* edge = (const float*)d_in[1];
    const int*   mask = (const int*)d_in[2];
    const float* kin  = (const float*)d_in[3];
    const float* Wq   = (const float*)d_in[4];
    const float* bq   = (const float*)d_in[5];
    const float* Wk   = (const float*)d_in[6];
    const float* Wv   = (const float*)d_in[7];
    const float* Wg   = (const float*)d_in[8];
    const float* lng  = (const float*)d_in[9];
    const float* lnb  = (const float*)d_in[10];
    const float* Wz   = (const float*)d_in[11];
    const float* Wo   = (const float*)d_in[12];
    float* out = (float*)d_out;

    char* ws = (char*)d_ws;
    const size_t qk_bytes = (size_t)B_ * H_ * N_ * HDP_ * 2;
    unsigned short* qp = (unsigned short*)ws;   ws += qk_bytes;
    unsigned short* kp = (unsigned short*)ws;   ws += qk_bytes;
    unsigned short* vT = (unsigned short*)ws;   ws += (size_t)B_ * H_ * HD_ * N_ * 2;
    float* gbuf = (float*)ws;                   ws += (size_t)B_ * N_ * D_ * 4;
    unsigned short* bias = (unsigned short*)ws; ws += (size_t)B_ * H_ * N_ * N_ * 2;
    unsigned short* Xhi = (unsigned short*)ws;  ws += (size_t)B_ * N_ * D_ * 2;
    unsigned short* Xlo = (unsigned short*)ws;  ws += (size_t)B_ * N_ * D_ * 2;
    unsigned short* Whi = (unsigned short*)ws;  ws += (size_t)D_ * D_ * 2;
    unsigned short* Wlo = (unsigned short*)ws;  ws += (size_t)D_ * D_ * 2;
    unsigned short* nb  = (unsigned short*)ws;  ws += (size_t)B_ * N_ * D_ * 2;
    unsigned short* kb  = (unsigned short*)ws;  ws += (size_t)B_ * N_ * D_ * 2;
    unsigned short* WqB = (unsigned short*)ws;  ws += (size_t)D_ * D_ * 2;
    unsigned short* WkB = (unsigned short*)ws;  ws += (size_t)D_ * D_ * 2;
    unsigned short* WvB = (unsigned short*)ws;  ws += (size_t)D_ * D_ * 2;
    unsigned short* WgB = (unsigned short*)ws;  ws += (size_t)D_ * D_ * 2;

    hipMemsetAsync(out, 0, (size_t)out_size * 4, stream);
    conv_prep<<<dim3(1536, 8), 256, 0, stream>>>(
        node, kin, Wq, Wk, Wv, Wg, Wo,
        nb, kb, WqB, WkB, WvB, WgB, Whi, Wlo, qp, kp);
    proj2_kernel<<<dim3(32, 12, 2), 256, 0, stream>>>(
        nb, kb, WqB, WkB, WvB, WgB, bq, qp, kp, vT, gbuf);
    bias_kernel<<<dim3(2048), 256, 0, stream>>>(edge, lng, lnb, Wz, mask, bias);
    attn_kernel<<<dim3(2048), 256, 0, stream>>>(qp, kp, vT, bias, gbuf, Xhi, Xlo);
    out_gemm2<<<dim3(32, 12, 2), 256, 0, stream>>>(Xhi, Xlo, Whi, Wlo, out);
}